// Round 4
// baseline (477.294 us; speedup 1.0000x reference)
//
#include <hip/hip_runtime.h>

// ---------------------------------------------------------------------------
// VoxelTripletLoss — Round 4: W conversion split out of the GEMM.
// B=64, M=2048, FEAT=512, N=32768.
//
//   K1 prep_conv: [0,1024)  W f32 -> W bf16 frag-image (LDS transpose) + wsqp
//                 [1024,1536) V -> (v_hi,v_lo) bf16 frag-image
//                 [1536,1600) exact v_sq[b]
//                 [1600,2128) 1/||anchor||, 1/||key||
//   K2 gemm2:    dotp[ns][b][m] via mfma_f32_32x32x16_bf16; pure DMA staging
//                (global_load_lds identity copies of frag images), no VALU.
//   K3 keydist:  keyp[b][m] = anchor.keys^T + wsq reduce
//   K4 rowpart:  per (b, m-slice) hardest pos/neg partials
//   K5 final:    combine -> masked mean -> d_out[0]
// ---------------------------------------------------------------------------

typedef __attribute__((ext_vector_type(8)))  short bf16x8;
typedef __attribute__((ext_vector_type(16))) float f32x16;

constexpr int   Mdim   = 2048;
constexpr int   Nvox   = 32768;
constexpr int   NS     = 32;        // k-splits for big GEMM
constexpr float BETA   = 0.8333333f;
constexpr float MARGIN = 0.2f;
constexpr float BIGV   = 1.0e9f;
constexpr int   WP     = 68;        // LDS f32 transpose pitch (16B-aligned)

// workspace layout (float offsets); total ~93 MB
constexpr size_t OFF_VSQ  = 0;                        // 64
constexpr size_t OFF_AINV = 64;                       // 64
constexpr size_t OFF_KINV = 128;                      // 2048
constexpr size_t OFF_WSQ  = 2176;                     // 2048
constexpr size_t OFF_WSQP = 4224;                     // NS*2048 = 65536
constexpr size_t OFF_PHP  = 69760;                    // 256
constexpr size_t OFF_PHN  = 70016;                    // 256
constexpr size_t OFF_PAP  = 70272;                    // 256
constexpr size_t OFF_PAN  = 70528;                    // 256
constexpr size_t OFF_KEYP = 70784;                    // 64*2048 = 131072
constexpr size_t OFF_DOTP = 201856;                   // NS*64*2048 = 4194304
constexpr size_t OFF_VHI  = 4396160;                  // 2M ushort = 1048576 fl
constexpr size_t OFF_VLO  = 5444736;                  // 1048576 fl
constexpr size_t OFF_WBF  = 6493312;                  // 64M ushort = 16777216 fl

__device__ __forceinline__ unsigned int bf16rne(float x) {
    unsigned int u = __float_as_uint(x);
    return (u + 0x7FFFu + ((u >> 16) & 1u)) >> 16;
}
__device__ __forceinline__ int pk2(unsigned int lo, unsigned int hi) {
    return (int)(lo | (hi << 16));
}
__device__ __forceinline__ void async16(const ushort* g, ushort* l) {
    __builtin_amdgcn_global_load_lds(
        (const __attribute__((address_space(1))) unsigned int*)g,
        (__attribute__((address_space(3))) unsigned int*)l, 16, 0, 0);
}

// frag image of a 64-row x 64-k tile (4096 ushorts):
//   idx = (row>>5)*2048 + ((k>>4)&3)*512 + ((row&31) + 32*((k>>3)&1))*8 + (k&7)

// ---------------------------------------------------------------------------
// K1 prep_conv (grid 2128)
// ---------------------------------------------------------------------------
__global__ __launch_bounds__(256) void prep_conv(
    const float* __restrict__ vox, const float* __restrict__ anc,
    const float* __restrict__ keys, const float* __restrict__ W,
    ushort* __restrict__ vhi, ushort* __restrict__ vlo, ushort* __restrict__ wbf,
    float* __restrict__ vsq, float* __restrict__ ainv, float* __restrict__ kinv,
    float* __restrict__ wsqp)
{
    const int tid  = threadIdx.x;
    const int lane = tid & 63;
    const int wave = tid >> 6;
    __shared__ float lds[64 * WP + 512];

    if (blockIdx.x < 1024) {
        // ---- W convert: block = (mb, 1024-k slice), 16 chunks of 64 k ----
        const int mb = blockIdx.x >> 5, sl = blockIdx.x & 31;
        const int r = tid >> 2, q = tid & 3;              // read: row r, 64B-line cluster q
        const float* wsrc = W + (size_t)(mb * 64 + r) * Nvox + sl * 1024;
        ushort* wdst = wbf + (size_t)(mb * 512 + sl * 16) * 4096;
        const int s_ = tid >> 6, kh = (tid >> 5) & 1, ml = tid & 31;
        const int rb0 = ml * WP + s_ * 16 + kh * 8;
        const int rb1 = (32 + ml) * WP + s_ * 16 + kh * 8;
        float wsqA = 0.f, wsqB = 0.f;
        for (int c = 0; c < 16; ++c) {
            const float4 a0 = *reinterpret_cast<const float4*>(wsrc + c * 64      + q * 4);
            const float4 a1 = *reinterpret_cast<const float4*>(wsrc + c * 64 + 16 + q * 4);
            const float4 a2 = *reinterpret_cast<const float4*>(wsrc + c * 64 + 32 + q * 4);
            const float4 a3 = *reinterpret_cast<const float4*>(wsrc + c * 64 + 48 + q * 4);
            __syncthreads();                      // prev readback done
            *reinterpret_cast<float4*>(&lds[r * WP      + q * 4]) = a0;
            *reinterpret_cast<float4*>(&lds[r * WP + 16 + q * 4]) = a1;
            *reinterpret_cast<float4*>(&lds[r * WP + 32 + q * 4]) = a2;
            *reinterpret_cast<float4*>(&lds[r * WP + 48 + q * 4]) = a3;
            __syncthreads();
            #pragma unroll
            for (int u = 0; u < 2; ++u) {
                const int rb = u ? rb1 : rb0;
                const float4 f0 = *reinterpret_cast<const float4*>(&lds[rb]);
                const float4 f1 = *reinterpret_cast<const float4*>(&lds[rb + 4]);
                const float e[8] = {f0.x, f0.y, f0.z, f0.w, f1.x, f1.y, f1.z, f1.w};
                unsigned int h[8];
                float wq = 0.f;
                #pragma unroll
                for (int i = 0; i < 8; ++i) {
                    wq = fmaf(e[i], e[i], wq);
                    h[i] = bf16rne(e[i]);
                }
                if (u) wsqB += wq; else wsqA += wq;
                const int4 pk = { pk2(h[0],h[1]), pk2(h[2],h[3]),
                                  pk2(h[4],h[5]), pk2(h[6],h[7]) };
                *reinterpret_cast<int4*>(wdst + (size_t)c * 4096 + (u * 256 + tid) * 8) = pk;
            }
        }
        __syncthreads();
        lds[64 * WP + ml * 8 + s_ * 2 + kh]        = wsqA;   // row ml
        lds[64 * WP + (32 + ml) * 8 + s_ * 2 + kh] = wsqB;   // row 32+ml
        __syncthreads();
        if (tid < 64) {
            float s = 0.f;
            #pragma unroll
            for (int i = 0; i < 8; ++i) s += lds[64 * WP + tid * 8 + i];
            wsqp[(size_t)sl * Mdim + mb * 64 + tid] = s;
        }
    } else if (blockIdx.x < 1536) {
        // ---- V convert (hi/lo) into frag images ----
        #pragma unroll
        for (int u = 0; u < 2; ++u) {
            const int uid = (blockIdx.x - 1024) * 8 + wave * 2 + u;
            const int bh = uid & 1, s = (uid >> 1) & 3, c = uid >> 3;
            const int b   = bh * 32 + (lane & 31);
            const int col = c * 64 + s * 16 + (lane >> 5) * 8;
            const float4* src = reinterpret_cast<const float4*>(vox + (size_t)b * Nvox + col);
            const float4 x0 = src[0], x1 = src[1];
            const float e[8] = {x0.x, x0.y, x0.z, x0.w, x1.x, x1.y, x1.z, x1.w};
            unsigned int h[8], l8[8];
            #pragma unroll
            for (int q = 0; q < 8; ++q) {
                const unsigned int hb = bf16rne(e[q]);
                h[q] = hb;
                l8[q] = bf16rne(e[q] - __uint_as_float(hb << 16));
            }
            const int4 hp = { pk2(h[0],h[1]), pk2(h[2],h[3]), pk2(h[4],h[5]), pk2(h[6],h[7]) };
            const int4 lp = { pk2(l8[0],l8[1]), pk2(l8[2],l8[3]), pk2(l8[4],l8[5]), pk2(l8[6],l8[7]) };
            const size_t base = (size_t)c * 4096 + bh * 2048 + s * 512 + lane * 8;
            *reinterpret_cast<int4*>(vhi + base) = hp;
            *reinterpret_cast<int4*>(vlo + base) = lp;
        }
    } else if (blockIdx.x < 1600) {
        // ---- exact v_sq ----
        const int b = blockIdx.x - 1536;
        const float4* src = reinterpret_cast<const float4*>(vox + (size_t)b * Nvox);
        float p = 0.f;
        for (int i = tid; i < Nvox / 4; i += 256) {
            const float4 x = src[i];
            p = fmaf(x.x, x.x, p); p = fmaf(x.y, x.y, p);
            p = fmaf(x.z, x.z, p); p = fmaf(x.w, x.w, p);
        }
        #pragma unroll
        for (int off = 32; off > 0; off >>= 1) p += __shfl_down(p, off);
        if (lane == 0) lds[wave] = p;
        __syncthreads();
        if (tid == 0) vsq[b] = lds[0] + lds[1] + lds[2] + lds[3];
    } else {
        // ---- feature-row norms ----
        const int r = (blockIdx.x - 1600) * 4 + wave;     // 0..2111
        const float* src = (r < 64) ? (anc + (size_t)r * 512)
                                    : (keys + (size_t)(r - 64) * 512);
        const float4* s4 = reinterpret_cast<const float4*>(src);
        const float4 x = s4[lane];
        const float4 y = s4[lane + 64];
        float p = 0.f;
        p = fmaf(x.x, x.x, p); p = fmaf(x.y, x.y, p);
        p = fmaf(x.z, x.z, p); p = fmaf(x.w, x.w, p);
        p = fmaf(y.x, y.x, p); p = fmaf(y.y, y.y, p);
        p = fmaf(y.z, y.z, p); p = fmaf(y.w, y.w, p);
        #pragma unroll
        for (int off = 32; off > 0; off >>= 1) p += __shfl_down(p, off);
        if (lane == 0) {
            const float inv = 1.f / fmaxf(sqrtf(p), 1e-8f);
            if (r < 64) ainv[r] = inv; else kinv[r - 64] = inv;
        }
    }
}

// ---------------------------------------------------------------------------
// K2: dotp[ns][64][2048]. 1024 blocks = 32 mb x 32 ns. Pure-DMA staging:
// per 64-k chunk: 6 async16 per wave (Vhi/Vlo/W frag images, identity copy),
// 12 ds_read_b128, 8 MFMA (vhi*w + vlo*w), 2 barriers. No VALU staging.
// ---------------------------------------------------------------------------
__global__ __launch_bounds__(256, 6) void gemm2(
    const ushort* __restrict__ vhi, const ushort* __restrict__ vlo,
    const ushort* __restrict__ wbf, float* __restrict__ dotp)
{
    __shared__ ushort sVhi[4096], sVlo[4096], sW[4096];   // 8 KB each

    const int tid  = threadIdx.x;
    const int lane = tid & 63;
    const int wave = tid >> 6;
    const int mb   = blockIdx.x & 31;
    const int ns   = blockIdx.x >> 5;

    const ushort* vhig = vhi + (size_t)(ns * 16) * 4096 + wave * 1024 + lane * 8;
    const ushort* vlog = vlo + (size_t)(ns * 16) * 4096 + wave * 1024 + lane * 8;
    const ushort* wg   = wbf + (size_t)(mb * 512 + ns * 16) * 4096 + wave * 1024 + lane * 8;
    ushort* dVhi = &sVhi[wave * 1024];   // wave-uniform DMA dests
    ushort* dVlo = &sVlo[wave * 1024];
    ushort* dW   = &sW[wave * 1024];

    const int wr = wave >> 1, wc = wave & 1;
    f32x16 acc = {};

    for (int ch = 0; ch < 16; ++ch) {
        __syncthreads();                 // all waves done reading prev chunk
        async16(vhig + (size_t)ch * 4096,       dVhi);
        async16(vhig + (size_t)ch * 4096 + 512, dVhi + 512);
        async16(vlog + (size_t)ch * 4096,       dVlo);
        async16(vlog + (size_t)ch * 4096 + 512, dVlo + 512);
        async16(wg   + (size_t)ch * 4096,       dW);
        async16(wg   + (size_t)ch * 4096 + 512, dW + 512);
        __syncthreads();                 // DMA drained & visible
        #pragma unroll
        for (int s = 0; s < 4; ++s) {
            const bf16x8 ah = *reinterpret_cast<const bf16x8*>(&sVhi[wr * 2048 + s * 512 + lane * 8]);
            const bf16x8 al = *reinterpret_cast<const bf16x8*>(&sVlo[wr * 2048 + s * 512 + lane * 8]);
            const bf16x8 bh = *reinterpret_cast<const bf16x8*>(&sW[wc * 2048 + s * 512 + lane * 8]);
            acc = __builtin_amdgcn_mfma_f32_32x32x16_bf16(ah, bh, acc, 0, 0, 0);
            acc = __builtin_amdgcn_mfma_f32_32x32x16_bf16(al, bh, acc, 0, 0, 0);
        }
    }

    // epilogue: C layout col=lane&31, row=(reg&3)+8*(reg>>2)+4*(lane>>5)
    const int col   = lane & 31;
    const int rbase = 4 * (lane >> 5);
    const size_t out_m = (size_t)(mb * 64 + wc * 32 + col);
    #pragma unroll
    for (int r = 0; r < 16; ++r) {
        const int row = (r & 3) + 8 * (r >> 2) + rbase;
        const int b   = wr * 32 + row;
        dotp[(size_t)(ns * 64 + b) * Mdim + out_m] = acc[r];
    }
}

// ---------------------------------------------------------------------------
// K3: blocks [0,256): key dots; blocks [256,264): wsq[m] = sum_s wsqp[s][m]
// ---------------------------------------------------------------------------
__global__ __launch_bounds__(256) void keydist_kernel(
    const float* __restrict__ anc, const float* __restrict__ keys,
    const float* __restrict__ wsqp, float* __restrict__ keyp,
    float* __restrict__ wsq)
{
    const int tid = threadIdx.x;
    if (blockIdx.x >= 256) {
        const int m = (blockIdx.x - 256) * 256 + tid;
        float s = 0.f;
        #pragma unroll
        for (int sp = 0; sp < NS; ++sp) s += wsqp[(size_t)sp * Mdim + m];
        wsq[m] = s;
        return;
    }
    __shared__ float kk[8 * 516];
    const int mt = blockIdx.x * 8;
    {
        const int row = tid >> 5, colb = (tid & 31) * 16;
        const float4* src = reinterpret_cast<const float4*>(keys + (size_t)(mt + row) * 512 + colb);
        #pragma unroll
        for (int j = 0; j < 4; ++j)
            *reinterpret_cast<float4*>(&kk[row * 516 + colb + j * 4]) = src[j];
    }
    __syncthreads();
    const int b = tid >> 2, msub = tid & 3;
    const float* arow = anc + (size_t)b * 512;
    const float* k0 = &kk[msub * 516];
    const float* k1 = &kk[(msub + 4) * 516];
    float d0 = 0.f, d1 = 0.f;
    for (int k = 0; k < 512; k += 4) {
        const float4 a = *reinterpret_cast<const float4*>(arow + k);
        const float4 x = *reinterpret_cast<const float4*>(k0 + k);
        const float4 y = *reinterpret_cast<const float4*>(k1 + k);
        d0 = fmaf(a.x, x.x, d0); d0 = fmaf(a.y, x.y, d0);
        d0 = fmaf(a.z, x.z, d0); d0 = fmaf(a.w, x.w, d0);
        d1 = fmaf(a.x, y.x, d1); d1 = fmaf(a.y, y.y, d1);
        d1 = fmaf(a.z, y.z, d1); d1 = fmaf(a.w, y.w, d1);
    }
    keyp[(size_t)b * Mdim + mt + msub]     = d0;
    keyp[(size_t)b * Mdim + mt + msub + 4] = d1;
}

// ---------------------------------------------------------------------------
// K4: grid 256 = 64 b x 4 m-slices (512 m each): partial hardest pos/neg
// ---------------------------------------------------------------------------
__global__ __launch_bounds__(256) void rowpart_kernel(
    const float* __restrict__ dotp, const float* __restrict__ wsq,
    const float* __restrict__ keyp, const float* __restrict__ vsq,
    const float* __restrict__ ainv, const float* __restrict__ kinv,
    float* __restrict__ php, float* __restrict__ phn,
    float* __restrict__ pap, float* __restrict__ pan)
{
    const int bid = blockIdx.x, tid = threadIdx.x;
    const int b = bid >> 2, sl = bid & 3;
    const float vs = vsq[b];
    const float ai = ainv[b];
    float hp = -BIGV, hn = BIGV, ap = 0.f, an = 0.f;
    #pragma unroll
    for (int rep = 0; rep < 2; ++rep) {
        const int m = sl * 512 + rep * 256 + tid;
        float dot = 0.f;
        #pragma unroll
        for (int s = 0; s < NS; ++s) dot += dotp[(size_t)(s * 64 + b) * Mdim + m];
        const float sv = 1.f - (vs + wsq[m] - 2.f * dot) * (1.f / 32768.f);
        const float kd = 1.f - keyp[(size_t)b * Mdim + m] * ai * kinv[m];
        if (sv > BETA) { ap = 1.f; hp = fmaxf(hp, kd); }
        if (sv < BETA) { an = 1.f; hn = fminf(hn, kd); }
    }
    #pragma unroll
    for (int off = 32; off > 0; off >>= 1) {
        hp = fmaxf(hp, __shfl_down(hp, off));
        hn = fminf(hn, __shfl_down(hn, off));
        ap = fmaxf(ap, __shfl_down(ap, off));
        an = fmaxf(an, __shfl_down(an, off));
    }
    __shared__ float sb[16];
    const int wv = tid >> 6;
    if ((tid & 63) == 0) {
        sb[wv * 4 + 0] = hp; sb[wv * 4 + 1] = hn;
        sb[wv * 4 + 2] = ap; sb[wv * 4 + 3] = an;
    }
    __syncthreads();
    if (tid == 0) {
        for (int w2 = 1; w2 < 4; ++w2) {
            hp = fmaxf(hp, sb[w2 * 4 + 0]);
            hn = fminf(hn, sb[w2 * 4 + 1]);
            ap = fmaxf(ap, sb[w2 * 4 + 2]);
            an = fmaxf(an, sb[w2 * 4 + 3]);
        }
        php[bid] = hp; phn[bid] = hn; pap[bid] = ap; pan[bid] = an;
    }
}

// ---------------------------------------------------------------------------
// K5: single block: combine 4 partials per b -> loss/valid -> masked mean
// ---------------------------------------------------------------------------
__global__ void final_kernel(const float* __restrict__ php, const float* __restrict__ phn,
                             const float* __restrict__ pap, const float* __restrict__ pan,
                             float* __restrict__ out)
{
    const int t = threadIdx.x;   // 256
    float hp = php[t], hn = phn[t], ap = pap[t], an = pan[t];
    hp = fmaxf(hp, __shfl_down(hp, 2)); hp = fmaxf(hp, __shfl_down(hp, 1));
    hn = fminf(hn, __shfl_down(hn, 2)); hn = fminf(hn, __shfl_down(hn, 1));
    ap = fmaxf(ap, __shfl_down(ap, 2)); ap = fmaxf(ap, __shfl_down(ap, 1));
    an = fmaxf(an, __shfl_down(an, 2)); an = fmaxf(an, __shfl_down(an, 1));
    __shared__ float sl[64], sc[64];
    if ((t & 3) == 0) {
        const int b = t >> 2;
        const float valid = (ap > 0.f && an > 0.f) ? 1.f : 0.f;
        sl[b] = fmaxf(hp - hn + MARGIN, 0.f) * valid;
        sc[b] = valid;
    }
    __syncthreads();
    if (t < 64) {
        float l = sl[t], c = sc[t];
        #pragma unroll
        for (int off = 32; off > 0; off >>= 1) {
            l += __shfl_down(l, off);
            c += __shfl_down(c, off);
        }
        if (t == 0) out[0] = (c > 0.f) ? (l / c) : 0.f;
    }
}

// ---------------------------------------------------------------------------
extern "C" void kernel_launch(void* const* d_in, const int* in_sizes, int n_in,
                              void* d_out, int out_size, void* d_ws, size_t ws_size,
                              hipStream_t stream) {
    const float* anchor = (const float*)d_in[0];   // (64, 512)
    const float* voxels = (const float*)d_in[1];   // (64, 32768)
    const float* keys   = (const float*)d_in[2];   // (2048, 512)
    const float* vals   = (const float*)d_in[3];   // (2048, 32768)

    float* ws = (float*)d_ws;
    float*  vsq  = ws + OFF_VSQ;
    float*  ainv = ws + OFF_AINV;
    float*  kinv = ws + OFF_KINV;
    float*  wsq  = ws + OFF_WSQ;
    float*  wsqp = ws + OFF_WSQP;
    float*  php  = ws + OFF_PHP;
    float*  phn  = ws + OFF_PHN;
    float*  pap  = ws + OFF_PAP;
    float*  pan  = ws + OFF_PAN;
    float*  keyp = ws + OFF_KEYP;
    float*  dotp = ws + OFF_DOTP;
    ushort* vhi  = (ushort*)(ws + OFF_VHI);
    ushort* vlo  = (ushort*)(ws + OFF_VLO);
    ushort* wbf  = (ushort*)(ws + OFF_WBF);

    prep_conv<<<2128, 256, 0, stream>>>(voxels, anchor, keys, vals,
                                        vhi, vlo, wbf, vsq, ainv, kinv, wsqp);
    gemm2<<<32 * NS, 256, 0, stream>>>(vhi, vlo, wbf, dotp);
    keydist_kernel<<<264, 256, 0, stream>>>(anchor, keys, wsqp, keyp, wsq);
    rowpart_kernel<<<256, 256, 0, stream>>>(dotp, wsq, keyp, vsq, ainv, kinv,
                                            php, phn, pap, pan);
    final_kernel<<<1, 256, 0, stream>>>(php, phn, pap, pan, (float*)d_out);
}

// Round 5
// 458.144 us; speedup vs baseline: 1.0418x; 1.0418x over previous
//
#include <hip/hip_runtime.h>

// ---------------------------------------------------------------------------
// VoxelTripletLoss — Round 5: barrier-free MFMA K-loop.
// B=64, M=2048, FEAT=512, N=32768.
//
//   K1 prep:    V -> (v_hi,v_lo) bf16 B-frag slices (128 x 256-k x 64b),
//               exact v_sq[b], 1/||anchor||, 1/||key||
//   K2 gemm3:   A = W rows streamed global->VGPR (convert in reg),
//               B = V-frag in LDS (preloaded once per 256-k phase).
//               Inner 16-chunk loop has NO barriers. Block = 128m x 64b,
//               k-extent 1024 (4 phases), grid 512 = 32 ns x 16 mb (2/CU).
//               dotp[ns][m][b] (+wsqp[ns][m]).
//   K3 keydist: keyp_t[m][b] = anchor.keys^T + wsq reduce
//   K4 rowpart: lane==b; hardest pos/neg partials per 8-m stripe
//   K5 final:   combine 256 stripes -> masked mean -> d_out[0]
// ---------------------------------------------------------------------------

typedef __attribute__((ext_vector_type(8)))  short bf16x8;
typedef __attribute__((ext_vector_type(16))) float f32x16;

constexpr int   Mdim   = 2048;
constexpr int   Nvox   = 32768;
constexpr int   NS     = 32;
constexpr float BETA   = 0.8333333f;
constexpr float MARGIN = 0.2f;
constexpr float BIGV   = 1.0e9f;

// workspace layout (float offsets); total ~26 MB
constexpr size_t OFF_VSQ  = 0;                        // 64
constexpr size_t OFF_AINV = 64;                       // 64
constexpr size_t OFF_KINV = 128;                      // 2048
constexpr size_t OFF_WSQ  = 2176;                     // 2048
constexpr size_t OFF_WSQP = 4224;                     // NS*2048 = 65536
constexpr size_t OFF_PHP  = 69760;                    // 256*64 = 16384
constexpr size_t OFF_PHN  = 86144;                    // 16384
constexpr size_t OFF_PAP  = 102528;                   // 16384
constexpr size_t OFF_PAN  = 118912;                   // 16384
constexpr size_t OFF_KEYPT= 135296;                   // 2048*64 = 131072
constexpr size_t OFF_DOTP = 266368;                   // NS*2048*64 = 4194304
constexpr size_t OFF_VF   = 4460672;                  // 4M ushort = 2097152 fl

__device__ __forceinline__ unsigned int bf16rne(float x) {
    unsigned int u = __float_as_uint(x);
    return (u + 0x7FFFu + ((u >> 16) & 1u)) >> 16;
}
__device__ __forceinline__ int pk2(unsigned int lo, unsigned int hi) {
    return (int)(lo | (hi << 16));
}
__device__ __forceinline__ void async16(const ushort* g, ushort* l) {
    __builtin_amdgcn_global_load_lds(
        (const __attribute__((address_space(1))) unsigned int*)g,
        (__attribute__((address_space(3))) unsigned int*)l, 16, 0, 0);
}

// V-frag global layout (ushort idx), per 256-k slice s (0..127):
//   s*32768 + dtype*16384 + ((k&255)>>3)*512 + b*8 + (k&7)
// B-frag read for chunk ch, tile t: lane l -> b = t*32 + (l&31),
//   k_local = ch*16 + (l>>5)*8 + j  =>  idx = (ch*2+(l>>5))*512 + t*256 + (l&31)*8

// ---------------------------------------------------------------------------
// K1 prep (grid 848)
//   [0,256):   V-frag convert (hi/lo). unit g = blk*16 + wave*4 + it covers
//              8 consecutive k for all 64 b (lane = b). 1 KB contig stores.
//   [256,320): exact v_sq[b]
//   [320,848): feature-row norms (4 rows per block)
// ---------------------------------------------------------------------------
__global__ __launch_bounds__(256) void prep_kernel(
    const float* __restrict__ vox, const float* __restrict__ anc,
    const float* __restrict__ keys, ushort* __restrict__ vf,
    float* __restrict__ vsq, float* __restrict__ ainv, float* __restrict__ kinv)
{
    const int tid = threadIdx.x;
    const int lane = tid & 63;
    const int wave = tid >> 6;
    __shared__ float sb[4];

    if (blockIdx.x < 256) {
        #pragma unroll
        for (int it = 0; it < 4; ++it) {
            const int g = blockIdx.x * 16 + wave * 4 + it;   // 0..4095
            const int k0 = g * 8;
            const int slice = g >> 5, gg = g & 31;
            const float4* src = reinterpret_cast<const float4*>(vox + (size_t)lane * Nvox + k0);
            const float4 x0 = src[0], x1 = src[1];
            const float e[8] = {x0.x, x0.y, x0.z, x0.w, x1.x, x1.y, x1.z, x1.w};
            unsigned int h[8], l8[8];
            #pragma unroll
            for (int q = 0; q < 8; ++q) {
                const unsigned int hb = bf16rne(e[q]);
                h[q] = hb;
                l8[q] = bf16rne(e[q] - __uint_as_float(hb << 16));
            }
            const int4 hp = { pk2(h[0],h[1]), pk2(h[2],h[3]), pk2(h[4],h[5]), pk2(h[6],h[7]) };
            const int4 lp = { pk2(l8[0],l8[1]), pk2(l8[2],l8[3]), pk2(l8[4],l8[5]), pk2(l8[6],l8[7]) };
            const size_t base = (size_t)slice * 32768 + gg * 512 + lane * 8;
            *reinterpret_cast<int4*>(vf + base)         = hp;
            *reinterpret_cast<int4*>(vf + base + 16384) = lp;
        }
    } else if (blockIdx.x < 320) {
        const int b = blockIdx.x - 256;
        const float4* src = reinterpret_cast<const float4*>(vox + (size_t)b * Nvox);
        float p = 0.f;
        for (int i = tid; i < Nvox / 4; i += 256) {
            const float4 x = src[i];
            p = fmaf(x.x, x.x, p); p = fmaf(x.y, x.y, p);
            p = fmaf(x.z, x.z, p); p = fmaf(x.w, x.w, p);
        }
        #pragma unroll
        for (int off = 32; off > 0; off >>= 1) p += __shfl_down(p, off);
        if (lane == 0) sb[wave] = p;
        __syncthreads();
        if (tid == 0) vsq[b] = sb[0] + sb[1] + sb[2] + sb[3];
    } else {
        const int r = (blockIdx.x - 320) * 4 + wave;     // 0..2111
        const float* src = (r < 64) ? (anc + (size_t)r * 512)
                                    : (keys + (size_t)(r - 64) * 512);
        const float4* s4 = reinterpret_cast<const float4*>(src);
        const float4 x = s4[lane];
        const float4 y = s4[lane + 64];
        float p = 0.f;
        p = fmaf(x.x, x.x, p); p = fmaf(x.y, x.y, p);
        p = fmaf(x.z, x.z, p); p = fmaf(x.w, x.w, p);
        p = fmaf(y.x, y.x, p); p = fmaf(y.y, y.y, p);
        p = fmaf(y.z, y.z, p); p = fmaf(y.w, y.w, p);
        #pragma unroll
        for (int off = 32; off > 0; off >>= 1) p += __shfl_down(p, off);
        if (lane == 0) {
            const float inv = 1.f / fmaxf(sqrtf(p), 1e-8f);
            if (r < 64) ainv[r] = inv; else kinv[r - 64] = inv;
        }
    }
}

// ---------------------------------------------------------------------------
// K2 gemm3 (grid 512 = 32 ns x 16 mb, 2 blocks/CU, all-resident)
// ---------------------------------------------------------------------------
__global__ __launch_bounds__(256, 2) void gemm3(
    const ushort* __restrict__ vf, const float* __restrict__ W,
    float* __restrict__ dotp, float* __restrict__ wsqp)
{
    __shared__ ushort sV[32768];     // 64 KB: [hi 16384][lo 16384]

    const int tid  = threadIdx.x;
    const int lane = tid & 63;
    const int wave = tid >> 6;
    const int mb   = blockIdx.x & 15;
    const int ns   = blockIdx.x >> 4;

    const int   mrow = mb * 128 + wave * 32 + (lane & 31);
    const float* wrow = W + (size_t)mrow * Nvox + ns * 1024 + (lane >> 5) * 8;

    f32x16 acc0 = {}, acc1 = {};
    float wsq = 0.f;

    for (int p = 0; p < 4; ++p) {
        if (p) __syncthreads();      // prior phase's LDS reads done
        const ushort* vg = vf + (size_t)(ns * 4 + p) * 32768 + wave * 512 + lane * 8;
        ushort* vl = &sV[wave * 512];
        #pragma unroll
        for (int r = 0; r < 16; ++r)
            async16(vg + r * 2048, vl + r * 2048);
        __syncthreads();             // DMA drained & visible

        const float* wp = wrow + p * 256;
        float4 wa = *reinterpret_cast<const float4*>(wp);
        float4 wb = *reinterpret_cast<const float4*>(wp + 4);
        #pragma unroll 4
        for (int ch = 0; ch < 16; ++ch) {
            const float e[8] = {wa.x, wa.y, wa.z, wa.w, wb.x, wb.y, wb.z, wb.w};
            unsigned int h[8];
            #pragma unroll
            for (int q = 0; q < 8; ++q) {
                wsq = fmaf(e[q], e[q], wsq);
                h[q] = bf16rne(e[q]);
            }
            int4 pk = { pk2(h[0],h[1]), pk2(h[2],h[3]), pk2(h[4],h[5]), pk2(h[6],h[7]) };
            const bf16x8 af = *reinterpret_cast<const bf16x8*>(&pk);
            if (ch < 15) {           // prefetch next chunk's W
                wa = *reinterpret_cast<const float4*>(wp + (ch + 1) * 16);
                wb = *reinterpret_cast<const float4*>(wp + (ch + 1) * 16 + 4);
            }
            const int ro = (ch * 2 + (lane >> 5)) * 512 + (lane & 31) * 8;
            const bf16x8 bh0 = *reinterpret_cast<const bf16x8*>(&sV[ro]);
            const bf16x8 bh1 = *reinterpret_cast<const bf16x8*>(&sV[ro + 256]);
            const bf16x8 bl0 = *reinterpret_cast<const bf16x8*>(&sV[16384 + ro]);
            const bf16x8 bl1 = *reinterpret_cast<const bf16x8*>(&sV[16384 + ro + 256]);
            acc0 = __builtin_amdgcn_mfma_f32_32x32x16_bf16(af, bh0, acc0, 0, 0, 0);
            acc0 = __builtin_amdgcn_mfma_f32_32x32x16_bf16(af, bl0, acc0, 0, 0, 0);
            acc1 = __builtin_amdgcn_mfma_f32_32x32x16_bf16(af, bh1, acc1, 0, 0, 0);
            acc1 = __builtin_amdgcn_mfma_f32_32x32x16_bf16(af, bl1, acc1, 0, 0, 0);
        }
    }

    // wsq: lanes l and l+32 hold halves of row (lane&31)
    wsq += __shfl_down(wsq, 32);
    if (lane < 32)
        wsqp[(size_t)ns * Mdim + mb * 128 + wave * 32 + lane] = wsq;

    // C layout: n-col = lane&31 (=> b), m-row = (r&3)+8*(r>>2)+4*(lane>>5)
    const int bcol = lane & 31;
    const int rb   = 4 * (lane >> 5);
    #pragma unroll
    for (int r = 0; r < 16; ++r) {
        const int m = mb * 128 + wave * 32 + (r & 3) + 8 * (r >> 2) + rb;
        float* dst = dotp + ((size_t)ns * Mdim + m) * 64;
        dst[bcol]      = acc0[r];
        dst[32 + bcol] = acc1[r];
    }
}

// ---------------------------------------------------------------------------
// K3 keydist (grid 264): [0,256): keyp_t[m][b]; [256,264): wsq reduce
// ---------------------------------------------------------------------------
__global__ __launch_bounds__(256) void keydist_kernel(
    const float* __restrict__ anc, const float* __restrict__ keys,
    const float* __restrict__ wsqp, float* __restrict__ keypt,
    float* __restrict__ wsq)
{
    const int tid = threadIdx.x;
    if (blockIdx.x >= 256) {
        const int m = (blockIdx.x - 256) * 256 + tid;
        float s = 0.f;
        #pragma unroll
        for (int sp = 0; sp < NS; ++sp) s += wsqp[(size_t)sp * Mdim + m];
        wsq[m] = s;
        return;
    }
    __shared__ float kk[8 * 516];
    const int mt = blockIdx.x * 8;
    {
        const int row = tid >> 5, colb = (tid & 31) * 16;
        const float4* src = reinterpret_cast<const float4*>(keys + (size_t)(mt + row) * 512 + colb);
        #pragma unroll
        for (int j = 0; j < 4; ++j)
            *reinterpret_cast<float4*>(&kk[row * 516 + colb + j * 4]) = src[j];
    }
    __syncthreads();
    const int b = tid & 63, mi = tid >> 6;
    const float* arow = anc + (size_t)b * 512;
    const float* k0 = &kk[mi * 516];
    const float* k1 = &kk[(mi + 4) * 516];
    float d0 = 0.f, d1 = 0.f;
    for (int k = 0; k < 512; k += 4) {
        const float4 a = *reinterpret_cast<const float4*>(arow + k);
        const float4 x = *reinterpret_cast<const float4*>(k0 + k);
        const float4 y = *reinterpret_cast<const float4*>(k1 + k);
        d0 = fmaf(a.x, x.x, d0); d0 = fmaf(a.y, x.y, d0);
        d0 = fmaf(a.z, x.z, d0); d0 = fmaf(a.w, x.w, d0);
        d1 = fmaf(a.x, y.x, d1); d1 = fmaf(a.y, y.y, d1);
        d1 = fmaf(a.z, y.z, d1); d1 = fmaf(a.w, y.w, d1);
    }
    keypt[(size_t)(mt + mi) * 64 + b]     = d0;
    keypt[(size_t)(mt + 4 + mi) * 64 + b] = d1;
}

// ---------------------------------------------------------------------------
// K4 rowpart (grid 256): lane == b; 8 m per block (2 per wave)
// ---------------------------------------------------------------------------
__global__ __launch_bounds__(256) void rowpart_kernel(
    const float* __restrict__ dotp, const float* __restrict__ wsq,
    const float* __restrict__ keypt, const float* __restrict__ vsq,
    const float* __restrict__ ainv, const float* __restrict__ kinv,
    float* __restrict__ php, float* __restrict__ phn,
    float* __restrict__ pap, float* __restrict__ pan)
{
    const int tid = threadIdx.x, lane = tid & 63, wave = tid >> 6;
    const int mbase = blockIdx.x * 8;
    const float vs = vsq[lane];
    const float ai = ainv[lane];
    float hp = -BIGV, hn = BIGV, ap = 0.f, an = 0.f;
    #pragma unroll
    for (int it = 0; it < 2; ++it) {
        const int m = mbase + it * 4 + wave;
        float dot = 0.f;
        #pragma unroll
        for (int s = 0; s < NS; ++s)
            dot += dotp[((size_t)s * Mdim + m) * 64 + lane];
        const float sv = 1.f - (vs + wsq[m] - 2.f * dot) * (1.f / 32768.f);
        const float kd = 1.f - keypt[(size_t)m * 64 + lane] * ai * kinv[m];
        if (sv > BETA) { ap = 1.f; hp = fmaxf(hp, kd); }
        if (sv < BETA) { an = 1.f; hn = fminf(hn, kd); }
    }
    __shared__ float red[4 * 64 * 4];
    red[(wave * 64 + lane) * 4 + 0] = hp;
    red[(wave * 64 + lane) * 4 + 1] = hn;
    red[(wave * 64 + lane) * 4 + 2] = ap;
    red[(wave * 64 + lane) * 4 + 3] = an;
    __syncthreads();
    if (tid < 64) {
        #pragma unroll
        for (int w = 1; w < 4; ++w) {
            hp = fmaxf(hp, red[(w * 64 + tid) * 4 + 0]);
            hn = fminf(hn, red[(w * 64 + tid) * 4 + 1]);
            ap = fmaxf(ap, red[(w * 64 + tid) * 4 + 2]);
            an = fmaxf(an, red[(w * 64 + tid) * 4 + 3]);
        }
        php[blockIdx.x * 64 + tid] = hp;
        phn[blockIdx.x * 64 + tid] = hn;
        pap[blockIdx.x * 64 + tid] = ap;
        pan[blockIdx.x * 64 + tid] = an;
    }
}

// ---------------------------------------------------------------------------
// K5 final: combine 256 stripes -> per-b loss/valid -> masked mean
// ---------------------------------------------------------------------------
__global__ void final_kernel(const float* __restrict__ php, const float* __restrict__ phn,
                             const float* __restrict__ pap, const float* __restrict__ pan,
                             float* __restrict__ out)
{
    const int t = threadIdx.x;           // 256
    const int b = t & 63, q = t >> 6;
    float hp = -BIGV, hn = BIGV, ap = 0.f, an = 0.f;
    for (int g = q; g < 256; g += 4) {
        hp = fmaxf(hp, php[g * 64 + b]);
        hn = fminf(hn, phn[g * 64 + b]);
        ap = fmaxf(ap, pap[g * 64 + b]);
        an = fmaxf(an, pan[g * 64 + b]);
    }
    __shared__ float R[256 * 4];
    R[t * 4 + 0] = hp; R[t * 4 + 1] = hn; R[t * 4 + 2] = ap; R[t * 4 + 3] = an;
    __syncthreads();
    if (t < 64) {
        #pragma unroll
        for (int q2 = 1; q2 < 4; ++q2) {
            hp = fmaxf(hp, R[((q2 << 6) + t) * 4 + 0]);
            hn = fminf(hn, R[((q2 << 6) + t) * 4 + 1]);
            ap = fmaxf(ap, R[((q2 << 6) + t) * 4 + 2]);
            an = fmaxf(an, R[((q2 << 6) + t) * 4 + 3]);
        }
        const float valid = (ap > 0.f && an > 0.f) ? 1.f : 0.f;
        float l = fmaxf(hp - hn + MARGIN, 0.f) * valid;
        float c = valid;
        #pragma unroll
        for (int off = 32; off > 0; off >>= 1) {
            l += __shfl_down(l, off);
            c += __shfl_down(c, off);
        }
        if (t == 0) out[0] = (c > 0.f) ? (l / c) : 0.f;
    }
}

// ---------------------------------------------------------------------------
extern "C" void kernel_launch(void* const* d_in, const int* in_sizes, int n_in,
                              void* d_out, int out_size, void* d_ws, size_t ws_size,
                              hipStream_t stream) {
    const float* anchor = (const float*)d_in[0];   // (64, 512)
    const float* voxels = (const float*)d_in[1];   // (64, 32768)
    const float* keys   = (const float*)d_in[2];   // (2048, 512)
    const float* vals   = (const float*)d_in[3];   // (2048, 32768)

    float* ws = (float*)d_ws;
    float*  vsq   = ws + OFF_VSQ;
    float*  ainv  = ws + OFF_AINV;
    float*  kinv  = ws + OFF_KINV;
    float*  wsq   = ws + OFF_WSQ;
    float*  wsqp  = ws + OFF_WSQP;
    float*  php   = ws + OFF_PHP;
    float*  phn   = ws + OFF_PHN;
    float*  pap   = ws + OFF_PAP;
    float*  pan   = ws + OFF_PAN;
    float*  keypt = ws + OFF_KEYPT;
    float*  dotp  = ws + OFF_DOTP;
    ushort* vf    = (ushort*)(ws + OFF_VF);

    prep_kernel<<<848, 256, 0, stream>>>(voxels, anchor, keys, vf, vsq, ainv, kinv);
    gemm3<<<512, 256, 0, stream>>>(vf, vals, dotp, wsqp);
    keydist_kernel<<<264, 256, 0, stream>>>(anchor, keys, wsqp, keypt, wsq);
    rowpart_kernel<<<256, 256, 0, stream>>>(dotp, wsq, keypt, vsq, ainv, kinv,
                                            php, phn, pap, pan);
    final_kernel<<<1, 256, 0, stream>>>(php, phn, pap, pan, (float*)d_out);
}